// Round 1
// baseline (3670.041 us; speedup 1.0000x reference)
//
#include <hip/hip_runtime.h>
#include <cstdint>
#include <cstddef>

#define EDIM  512
#define NROWS 16384
#define NE    8192
#define XQSZ  (NROWS * EDIM)   // 8388608

#define BM 64
#define BN 64
#define DC 64
#define SPLIT 4
#define CPB (NE / SPLIT)       // 2048 codes per block

// workspace byte offsets
#define OFF_ACC  0
#define OFF_Z    256
#define OFF_C2   (OFF_Z + NROWS * 4)          // 65792
#define OFF_KEYS (OFF_C2 + NE * 4)            // 98560 (8-aligned)

// Row sum-of-squares replicating numpy pairwise summation for n=512:
// ((S0+S1)+(S2+S3)) with each S_b an 8-way-unrolled 128-block.
// fp contract OFF so v*v rounds before the add (matches np square-then-sum).
__global__ void k_rownorm(const float* __restrict__ in, float* __restrict__ out, int nrows) {
#pragma clang fp contract(off)
    int row = blockIdx.x * blockDim.x + threadIdx.x;
    if (row >= nrows) return;
    const float* p = in + (size_t)row * EDIM;
    float S[4];
#pragma unroll
    for (int b = 0; b < 4; ++b) {
        const float* q = p + b * 128;
        float r[8];
#pragma unroll
        for (int j = 0; j < 8; ++j) { float v = q[j]; r[j] = v * v; }
        for (int i = 8; i < 128; i += 8) {
#pragma unroll
            for (int j = 0; j < 8; ++j) { float v = q[i + j]; r[j] = r[j] + v * v; }
        }
        S[b] = ((r[0] + r[1]) + (r[2] + r[3])) + ((r[4] + r[5]) + (r[6] + r[7]));
    }
    out[row] = (S[0] + S[1]) + (S[2] + S[3]);
}

// 64x64 tile GEMM-argmin. Block: 256 threads (16x16), 4x4 outputs/thread.
// Each block handles BM rows x CPB codes; SPLIT blocks per row-tile.
// Per-row argmin kept as packed u64 key: (f32 bits of d << 13) | code_idx,
// giving min-d with first-index tie-break (d is always positive here).
__global__ __launch_bounds__(256) void k_argmin(
        const float* __restrict__ x, const float* __restrict__ W,
        const float* __restrict__ Z, const float* __restrict__ c2,
        unsigned long long* __restrict__ keys) {
    __shared__ float A[DC][BM];
    __shared__ float B[DC][BN];
    __shared__ float Zs[BM];
    __shared__ unsigned long long kb[BM][17];

    const int tid = threadIdx.x;
    const int tx = tid & 15, ty = tid >> 4;
    const int rowtile = blockIdx.x / SPLIT;
    const int csplit  = blockIdx.x % SPLIT;
    const int row0 = rowtile * BM;
    const int code0 = csplit * CPB;

    if (tid < BM) Zs[tid] = Z[row0 + tid];

    unsigned long long key[4];
#pragma unroll
    for (int i = 0; i < 4; ++i) key[i] = ~0ull;

    const int q = tid & 15;      // float4 column within 64-wide d chunk
    const int r = tid >> 4;      // base row

    for (int nt = 0; nt < CPB / BN; ++nt) {
        const int j0 = code0 + nt * BN;
        float acc[4][4];
#pragma unroll
        for (int i = 0; i < 4; ++i)
#pragma unroll
            for (int j = 0; j < 4; ++j) acc[i][j] = 0.0f;

        for (int dc = 0; dc < EDIM / DC; ++dc) {
            const int d0 = dc * DC;
            // stage A (x rows) and B (W rows) transposed: LDS[d][m]
#pragma unroll
            for (int s = 0; s < 4; ++s) {
                const int rr = r + 16 * s;
                const float4 av = *(const float4*)(x + (size_t)(row0 + rr) * EDIM + d0 + q * 4);
                A[q * 4 + 0][rr] = av.x; A[q * 4 + 1][rr] = av.y;
                A[q * 4 + 2][rr] = av.z; A[q * 4 + 3][rr] = av.w;
                const float4 bv = *(const float4*)(W + (size_t)(j0 + rr) * EDIM + d0 + q * 4);
                B[q * 4 + 0][rr] = bv.x; B[q * 4 + 1][rr] = bv.y;
                B[q * 4 + 2][rr] = bv.z; B[q * 4 + 3][rr] = bv.w;
            }
            __syncthreads();
#pragma unroll
            for (int d = 0; d < DC; ++d) {
                const float4 a4 = *(const float4*)&A[d][ty * 4];
                const float4 b4 = *(const float4*)&B[d][tx * 4];
                acc[0][0] += a4.x * b4.x; acc[0][1] += a4.x * b4.y;
                acc[0][2] += a4.x * b4.z; acc[0][3] += a4.x * b4.w;
                acc[1][0] += a4.y * b4.x; acc[1][1] += a4.y * b4.y;
                acc[1][2] += a4.y * b4.z; acc[1][3] += a4.y * b4.w;
                acc[2][0] += a4.z * b4.x; acc[2][1] += a4.z * b4.y;
                acc[2][2] += a4.z * b4.z; acc[2][3] += a4.z * b4.w;
                acc[3][0] += a4.w * b4.x; acc[3][1] += a4.w * b4.y;
                acc[3][2] += a4.w * b4.z; acc[3][3] += a4.w * b4.w;
            }
            __syncthreads();
        }
        // epilogue: d = (Z + c2) - 2*m  (x2 exact, so contraction is harmless)
#pragma unroll
        for (int mi = 0; mi < 4; ++mi) {
            const float Zr = Zs[ty * 4 + mi];
#pragma unroll
            for (int ji = 0; ji < 4; ++ji) {
                const int j = j0 + tx * 4 + ji;
                const float t = Zr + c2[j];
                const float dd = t - 2.0f * acc[mi][ji];
                const unsigned long long k =
                    (((unsigned long long)__float_as_uint(dd)) << 13) | (unsigned)j;
                if (k < key[mi]) key[mi] = k;
            }
        }
    }

    // merge across the 16 tx-threads sharing each row
#pragma unroll
    for (int mi = 0; mi < 4; ++mi) kb[ty * 4 + mi][tx] = key[mi];
    __syncthreads();
    if (tid < BM) {
        unsigned long long m = kb[tid][0];
#pragma unroll
        for (int t = 1; t < 16; ++t) { unsigned long long v = kb[tid][t]; if (v < m) m = v; }
        keys[(size_t)(row0 + tid) * SPLIT + csplit] = m;
    }
}

// Gather x_q = W[idx], STE output x + (w - x), loss partial sums, index write.
__global__ __launch_bounds__(256) void k_gather(
        const float* __restrict__ x, const float* __restrict__ W,
        const unsigned long long* __restrict__ keys,
        float* __restrict__ out, double* __restrict__ acc) {
    const int row = blockIdx.x;
    unsigned long long m = keys[(size_t)row * SPLIT + 0];
#pragma unroll
    for (int s = 1; s < SPLIT; ++s) {
        unsigned long long v = keys[(size_t)row * SPLIT + s];
        if (v < m) m = v;
    }
    const int idx = (int)(m & 0x1FFFull);

    const float* wrow = W + (size_t)idx * EDIM;
    const float* xrow = x + (size_t)row * EDIM;
    float* orow = out + (size_t)row * EDIM;

    double lsum = 0.0;
    for (int c = threadIdx.x; c < EDIM; c += 256) {
        const float xv = xrow[c];
        const float wv = wrow[c];
        const float t = wv - xv;       // f32 round, matches np (x_q - x)
        orow[c] = xv + t;              // f32 round, matches np STE output
        lsum += (double)t * (double)t;
    }
    // block reduce (4 waves of 64)
#pragma unroll
    for (int off = 32; off > 0; off >>= 1) lsum += __shfl_down(lsum, off, 64);
    __shared__ double part[4];
    const int lane = threadIdx.x & 63, w = threadIdx.x >> 6;
    if (lane == 0) part[w] = lsum;
    __syncthreads();
    if (threadIdx.x == 0) {
        atomicAdd(acc, part[0] + part[1] + part[2] + part[3]);
        out[XQSZ + 1 + row] = (float)idx;   // indices output (as f32 values)
    }
}

__global__ void k_finalize(float* __restrict__ out, const double* __restrict__ acc) {
    out[XQSZ] = (float)(0.25 * acc[0] / (double)XQSZ);
}

extern "C" void kernel_launch(void* const* d_in, const int* in_sizes, int n_in,
                              void* d_out, int out_size, void* d_ws, size_t ws_size,
                              hipStream_t stream) {
    const float* x = (const float*)d_in[0];
    // d_in[1] = label (unused), d_in[2] = idx (unused)
    const float* W = (const float*)d_in[3];
    float* out = (float*)d_out;
    char* ws = (char*)d_ws;

    double* acc = (double*)(ws + OFF_ACC);
    float* Z    = (float*)(ws + OFF_Z);
    float* c2   = (float*)(ws + OFF_C2);
    unsigned long long* keys = (unsigned long long*)(ws + OFF_KEYS);

    hipMemsetAsync(acc, 0, sizeof(double), stream);
    k_rownorm<<<(NROWS + 255) / 256, 256, 0, stream>>>(x, Z, NROWS);
    k_rownorm<<<(NE + 255) / 256, 256, 0, stream>>>(W, c2, NE);
    k_argmin<<<dim3((NROWS / BM) * SPLIT), 256, 0, stream>>>(x, W, Z, c2, keys);
    k_gather<<<NROWS, 256, 0, stream>>>(x, W, keys, out, acc);
    k_finalize<<<1, 1, 0, stream>>>(out, acc);
}

// Round 2
// 2251.467 us; speedup vs baseline: 1.6301x; 1.6301x over previous
//
#include <hip/hip_runtime.h>
#include <cstdint>
#include <cstddef>

#define EDIM  512
#define NROWS 16384
#define NE    8192
#define XQSZ  (NROWS * EDIM)   // 8388608

#define BM 64
#define BN 64
#define DC 64
#define SPLIT 4
#define CPB (NE / SPLIT)       // 2048 codes per block

// workspace byte offsets
#define OFF_ACC  0
#define OFF_Z    256
#define OFF_C2   (OFF_Z + NROWS * 4)          // 65792
#define OFF_KEYS (OFF_C2 + NE * 4)            // 98560 (8-aligned)

// Row sum-of-squares replicating numpy pairwise summation for n=512:
// ((S0+S1)+(S2+S3)) with each S_b an 8-way-unrolled 128-block.
// fp contract OFF so v*v rounds before the add (matches np square-then-sum).
__global__ void k_rownorm(const float* __restrict__ in, float* __restrict__ out, int nrows) {
#pragma clang fp contract(off)
    int row = blockIdx.x * blockDim.x + threadIdx.x;
    if (row >= nrows) return;
    const float* p = in + (size_t)row * EDIM;
    float S[4];
#pragma unroll
    for (int b = 0; b < 4; ++b) {
        const float* q = p + b * 128;
        float r[8];
#pragma unroll
        for (int j = 0; j < 8; ++j) { float v = q[j]; r[j] = v * v; }
        for (int i = 8; i < 128; i += 8) {
#pragma unroll
            for (int j = 0; j < 8; ++j) { float v = q[i + j]; r[j] = r[j] + v * v; }
        }
        S[b] = ((r[0] + r[1]) + (r[2] + r[3])) + ((r[4] + r[5]) + (r[6] + r[7]));
    }
    out[row] = (S[0] + S[1]) + (S[2] + S[3]);
}

// 64x64 tile GEMM-argmin. Block: 256 threads (16x16), 4x4 outputs/thread.
// LDS tiles stored transposed [d][m] with XOR column swizzle:
//   physical col = logical col ^ (((d>>2)&7)<<2)
// -> transpose scalar writes hit 32 distinct banks (2 lanes/bank = free),
//    b128 reads stay 16B-aligned and conflict-free.
__global__ __launch_bounds__(256) void k_argmin(
        const float* __restrict__ x, const float* __restrict__ W,
        const float* __restrict__ Z, const float* __restrict__ c2,
        unsigned long long* __restrict__ keys) {
    __shared__ __align__(16) unsigned char smem[(DC * BM + DC * BN + BM) * 4];
    float (*A)[BM] = reinterpret_cast<float (*)[BM]>(smem);
    float (*B)[BN] = reinterpret_cast<float (*)[BN]>(smem + DC * BM * 4);
    float* Zs      = reinterpret_cast<float*>(smem + (DC * BM + DC * BN) * 4);
    // kb overlays A: only used after the final tile sync, 8704 B <= 16384 B
    unsigned long long (*kb)[17] = reinterpret_cast<unsigned long long (*)[17]>(smem);

    const int tid = threadIdx.x;
    const int tx = tid & 15, ty = tid >> 4;
    const int rowtile = blockIdx.x / SPLIT;
    const int csplit  = blockIdx.x % SPLIT;
    const int row0 = rowtile * BM;
    const int code0 = csplit * CPB;

    if (tid < BM) Zs[tid] = Z[row0 + tid];
    __syncthreads();   // Zs (shares smem region boundaries) ready before use

    unsigned long long key[4];
#pragma unroll
    for (int i = 0; i < 4; ++i) key[i] = ~0ull;

    const int q = tid & 15;      // float4 column within 64-wide d chunk
    const int r = tid >> 4;      // base row
    const int csw = (q & 7) << 2;  // write-side swizzle (row group = q)

    for (int nt = 0; nt < CPB / BN; ++nt) {
        const int j0 = code0 + nt * BN;
        float acc[4][4];
#pragma unroll
        for (int i = 0; i < 4; ++i)
#pragma unroll
            for (int j = 0; j < 4; ++j) acc[i][j] = 0.0f;

        for (int dc = 0; dc < EDIM / DC; ++dc) {
            const int d0 = dc * DC;
            // stage A (x rows) and B (W rows) transposed+swizzled
#pragma unroll
            for (int s = 0; s < 4; ++s) {
                const int rr = r + 16 * s;
                const int ca = rr ^ csw;
                const float4 av = *(const float4*)(x + (size_t)(row0 + rr) * EDIM + d0 + q * 4);
                A[q * 4 + 0][ca] = av.x; A[q * 4 + 1][ca] = av.y;
                A[q * 4 + 2][ca] = av.z; A[q * 4 + 3][ca] = av.w;
                const float4 bv = *(const float4*)(W + (size_t)(j0 + rr) * EDIM + d0 + q * 4);
                B[q * 4 + 0][ca] = bv.x; B[q * 4 + 1][ca] = bv.y;
                B[q * 4 + 2][ca] = bv.z; B[q * 4 + 3][ca] = bv.w;
            }
            __syncthreads();
#pragma unroll
            for (int dg = 0; dg < DC / 4; ++dg) {
                const int sw = (dg & 7) << 2;
                const int ca = (ty * 4) ^ sw;
                const int cb = (tx * 4) ^ sw;
#pragma unroll
                for (int dd = 0; dd < 4; ++dd) {
                    const int d = dg * 4 + dd;
                    const float4 a4 = *(const float4*)&A[d][ca];
                    const float4 b4 = *(const float4*)&B[d][cb];
                    acc[0][0] += a4.x * b4.x; acc[0][1] += a4.x * b4.y;
                    acc[0][2] += a4.x * b4.z; acc[0][3] += a4.x * b4.w;
                    acc[1][0] += a4.y * b4.x; acc[1][1] += a4.y * b4.y;
                    acc[1][2] += a4.y * b4.z; acc[1][3] += a4.y * b4.w;
                    acc[2][0] += a4.z * b4.x; acc[2][1] += a4.z * b4.y;
                    acc[2][2] += a4.z * b4.z; acc[2][3] += a4.z * b4.w;
                    acc[3][0] += a4.w * b4.x; acc[3][1] += a4.w * b4.y;
                    acc[3][2] += a4.w * b4.z; acc[3][3] += a4.w * b4.w;
                }
            }
            __syncthreads();
        }
        // epilogue: d = (Z + c2) - 2*m  (x2 exact, so contraction is harmless)
#pragma unroll
        for (int mi = 0; mi < 4; ++mi) {
            const float Zr = Zs[ty * 4 + mi];
#pragma unroll
            for (int ji = 0; ji < 4; ++ji) {
                const int j = j0 + tx * 4 + ji;
                const float t = Zr + c2[j];
                const float dd = t - 2.0f * acc[mi][ji];
                const unsigned long long k =
                    (((unsigned long long)__float_as_uint(dd)) << 13) | (unsigned)j;
                if (k < key[mi]) key[mi] = k;
            }
        }
    }

    // merge across the 16 tx-threads sharing each row (kb overlays A)
    __syncthreads();
#pragma unroll
    for (int mi = 0; mi < 4; ++mi) kb[ty * 4 + mi][tx] = key[mi];
    __syncthreads();
    if (tid < BM) {
        unsigned long long m = kb[tid][0];
#pragma unroll
        for (int t = 1; t < 16; ++t) { unsigned long long v = kb[tid][t]; if (v < m) m = v; }
        keys[(size_t)(row0 + tid) * SPLIT + csplit] = m;
    }
}

// Gather x_q = W[idx], STE output x + (w - x), loss partial sums, index write.
__global__ __launch_bounds__(256) void k_gather(
        const float* __restrict__ x, const float* __restrict__ W,
        const unsigned long long* __restrict__ keys,
        float* __restrict__ out, double* __restrict__ acc) {
    const int row = blockIdx.x;
    unsigned long long m = keys[(size_t)row * SPLIT + 0];
#pragma unroll
    for (int s = 1; s < SPLIT; ++s) {
        unsigned long long v = keys[(size_t)row * SPLIT + s];
        if (v < m) m = v;
    }
    const int idx = (int)(m & 0x1FFFull);

    const float* wrow = W + (size_t)idx * EDIM;
    const float* xrow = x + (size_t)row * EDIM;
    float* orow = out + (size_t)row * EDIM;

    double lsum = 0.0;
    for (int c = threadIdx.x; c < EDIM; c += 256) {
        const float xv = xrow[c];
        const float wv = wrow[c];
        const float t = wv - xv;       // f32 round, matches np (x_q - x)
        orow[c] = xv + t;              // f32 round, matches np STE output
        lsum += (double)t * (double)t;
    }
    // block reduce (4 waves of 64)
#pragma unroll
    for (int off = 32; off > 0; off >>= 1) lsum += __shfl_down(lsum, off, 64);
    __shared__ double part[4];
    const int lane = threadIdx.x & 63, w = threadIdx.x >> 6;
    if (lane == 0) part[w] = lsum;
    __syncthreads();
    if (threadIdx.x == 0) {
        atomicAdd(acc, part[0] + part[1] + part[2] + part[3]);
        out[XQSZ + 1 + row] = (float)idx;   // indices output (as f32 values)
    }
}

__global__ void k_finalize(float* __restrict__ out, const double* __restrict__ acc) {
    out[XQSZ] = (float)(0.25 * acc[0] / (double)XQSZ);
}

extern "C" void kernel_launch(void* const* d_in, const int* in_sizes, int n_in,
                              void* d_out, int out_size, void* d_ws, size_t ws_size,
                              hipStream_t stream) {
    const float* x = (const float*)d_in[0];
    // d_in[1] = label (unused), d_in[2] = idx (unused)
    const float* W = (const float*)d_in[3];
    float* out = (float*)d_out;
    char* ws = (char*)d_ws;

    double* acc = (double*)(ws + OFF_ACC);
    float* Z    = (float*)(ws + OFF_Z);
    float* c2   = (float*)(ws + OFF_C2);
    unsigned long long* keys = (unsigned long long*)(ws + OFF_KEYS);

    hipMemsetAsync(acc, 0, sizeof(double), stream);
    k_rownorm<<<(NROWS + 255) / 256, 256, 0, stream>>>(x, Z, NROWS);
    k_rownorm<<<(NE + 255) / 256, 256, 0, stream>>>(W, c2, NE);
    k_argmin<<<dim3((NROWS / BM) * SPLIT), 256, 0, stream>>>(x, W, Z, c2, keys);
    k_gather<<<NROWS, 256, 0, stream>>>(x, W, keys, out, acc);
    k_finalize<<<1, 1, 0, stream>>>(out, acc);
}

// Round 4
// 1936.954 us; speedup vs baseline: 1.8947x; 1.1624x over previous
//
#include <hip/hip_runtime.h>
#include <cstdint>
#include <cstddef>

#define EDIM  512
#define NROWS 16384
#define NE    8192
#define XQSZ  (NROWS * EDIM)   // 8388608

#define BM 128
#define BN 128
#define DC 32
#define SPLIT 8
#define CPB (NE / SPLIT)       // 1024 codes per block
#define NT  (CPB / BN)         // 8 code tiles per block

// workspace byte offsets
#define OFF_ACC  0
#define OFF_Z    256
#define OFF_C2   (OFF_Z + NROWS * 4)          // 65792
#define OFF_KEYS (OFF_C2 + NE * 4)            // 98560 (8-aligned)

// Row sum-of-squares replicating numpy pairwise summation for n=512.
__global__ void k_rownorm(const float* __restrict__ in, float* __restrict__ out, int nrows) {
#pragma clang fp contract(off)
    int row = blockIdx.x * blockDim.x + threadIdx.x;
    if (row >= nrows) return;
    const float* p = in + (size_t)row * EDIM;
    float S[4];
#pragma unroll
    for (int b = 0; b < 4; ++b) {
        const float* q = p + b * 128;
        float r[8];
#pragma unroll
        for (int j = 0; j < 8; ++j) { float v = q[j]; r[j] = v * v; }
        for (int i = 8; i < 128; i += 8) {
#pragma unroll
            for (int j = 0; j < 8; ++j) { float v = q[i + j]; r[j] = r[j] + v * v; }
        }
        S[b] = ((r[0] + r[1]) + (r[2] + r[3])) + ((r[4] + r[5]) + (r[6] + r[7]));
    }
    out[row] = (S[0] + S[1]) + (S[2] + S[3]);
}

// 128x128 tile GEMM-argmin, 8x8 per thread (256 threads as 16x16), DC=32.
// LDS tiles transposed [d][col], swizzled:
//   phys(d,col) = col ^ (((d>>2)&7)<<2) ^ (((col>>5)&3)<<2)
// (round-3 bug: A-read omitted the ((col>>5)&3)<<2 term for ty>=4 — fixed)
// Writes: 2 lanes/bank (free). A-reads: 4 b128 broadcasts/wave, conflict-free.
// B-reads: 2-way (free). Accumulation order over d is IDENTICAL to the
// round-2 kernel -> bitwise-identical distances/argmin.
__global__ __launch_bounds__(256, 4) void k_argmin(
        const float* __restrict__ x, const float* __restrict__ W,
        const float* __restrict__ Z, const float* __restrict__ c2,
        unsigned long long* __restrict__ keys) {
    __shared__ __align__(16) unsigned char smem[(DC * BM + DC * BN + BM) * 4];
    float (*A)[BM] = reinterpret_cast<float (*)[BM]>(smem);
    float (*B)[BN] = reinterpret_cast<float (*)[BN]>(smem + DC * BM * 4);
    float* Zs      = reinterpret_cast<float*>(smem + (DC * BM + DC * BN) * 4);
    // kb overlays A+B (32 KB), used only after the final compute barrier
    unsigned long long (*kb)[17] = reinterpret_cast<unsigned long long (*)[17]>(smem);

    const int tid = threadIdx.x;
    const int tx = tid & 15, ty = tid >> 4;
    const int rowtile = blockIdx.x & (NROWS / BM - 1);
    const int csplit  = blockIdx.x >> 7;          // 128 rowtiles
    const int row0 = rowtile * BM;
    const int code0 = csplit * CPB;

    if (tid < BM) Zs[tid] = Z[row0 + tid];
    __syncthreads();

    unsigned long long key[8];
#pragma unroll
    for (int i = 0; i < 8; ++i) key[i] = ~0ull;

    const int qa = tid & 7;      // float4 d-offset within 32-wide chunk
    const int ra = tid >> 3;     // base col (row-of-x / code-of-W), 0..31
    const int wsw = qa << 2;     // write-side d-group swizzle

    for (int nt = 0; nt < NT; ++nt) {
        const int j0 = code0 + nt * BN;
        float acc[8][8];
#pragma unroll
        for (int i = 0; i < 8; ++i)
#pragma unroll
            for (int j = 0; j < 8; ++j) acc[i][j] = 0.0f;

        for (int dc = 0; dc < EDIM / DC; ++dc) {
            const int d0 = dc * DC;
#pragma unroll
            for (int s = 0; s < 4; ++s) {
                const int rr = ra + 32 * s;
                const int pc = rr ^ wsw ^ ((s & 3) << 2);   // phys col
                const float4 av = *(const float4*)(x + (size_t)(row0 + rr) * EDIM + d0 + qa * 4);
                A[qa * 4 + 0][pc] = av.x; A[qa * 4 + 1][pc] = av.y;
                A[qa * 4 + 2][pc] = av.z; A[qa * 4 + 3][pc] = av.w;
                const float4 bv = *(const float4*)(W + (size_t)(j0 + rr) * EDIM + d0 + qa * 4);
                B[qa * 4 + 0][pc] = bv.x; B[qa * 4 + 1][pc] = bv.y;
                B[qa * 4 + 2][pc] = bv.z; B[qa * 4 + 3][pc] = bv.w;
            }
            __syncthreads();
#pragma unroll
            for (int dg = 0; dg < DC / 4; ++dg) {
                const int sw = (dg & 7) << 2;
                const int ca0 = ty * 8;
                const int pa0 = ca0 ^ sw ^ (((ca0 >> 5) & 3) << 2);
                const int pa1 = pa0 ^ 4;
                const int cb0 = tx * 8;
                const int pb0 = cb0 ^ sw ^ (((cb0 >> 5) & 3) << 2);
                const int pb1 = pb0 ^ 4;
#pragma unroll
                for (int dd = 0; dd < 4; ++dd) {
                    const int d = dg * 4 + dd;
                    const float4 a0 = *(const float4*)&A[d][pa0];
                    const float4 a1 = *(const float4*)&A[d][pa1];
                    const float4 b0 = *(const float4*)&B[d][pb0];
                    const float4 b1 = *(const float4*)&B[d][pb1];
                    const float a[8] = {a0.x, a0.y, a0.z, a0.w, a1.x, a1.y, a1.z, a1.w};
                    const float b[8] = {b0.x, b0.y, b0.z, b0.w, b1.x, b1.y, b1.z, b1.w};
#pragma unroll
                    for (int i = 0; i < 8; ++i)
#pragma unroll
                        for (int j = 0; j < 8; ++j)
                            acc[i][j] += a[i] * b[j];
                }
            }
            __syncthreads();
        }
        // epilogue: d = (Z + c2) - 2*m
#pragma unroll
        for (int mi = 0; mi < 8; ++mi) {
            const float Zr = Zs[ty * 8 + mi];
#pragma unroll
            for (int ji = 0; ji < 8; ++ji) {
                const int j = j0 + tx * 8 + ji;
                const float t = Zr + c2[j];
                const float dd = t - 2.0f * acc[mi][ji];
                const unsigned long long k =
                    (((unsigned long long)__float_as_uint(dd)) << 13) | (unsigned)j;
                if (k < key[mi]) key[mi] = k;
            }
        }
    }

    // merge across the 16 tx-threads sharing each row (kb overlays A/B)
    __syncthreads();
#pragma unroll
    for (int mi = 0; mi < 8; ++mi) kb[ty * 8 + mi][tx] = key[mi];
    __syncthreads();
    if (tid < BM) {
        unsigned long long m = kb[tid][0];
#pragma unroll
        for (int t = 1; t < 16; ++t) { unsigned long long v = kb[tid][t]; if (v < m) m = v; }
        atomicMin(&keys[row0 + tid], m);
    }
}

// Gather x_q = W[idx], STE output x + (w - x), loss partial sums, index write.
__global__ __launch_bounds__(256) void k_gather(
        const float* __restrict__ x, const float* __restrict__ W,
        const unsigned long long* __restrict__ keys,
        float* __restrict__ out, double* __restrict__ acc) {
    const int row = blockIdx.x;
    const int idx = (int)(keys[row] & 0x1FFFull);

    const float* wrow = W + (size_t)idx * EDIM;
    const float* xrow = x + (size_t)row * EDIM;
    float* orow = out + (size_t)row * EDIM;

    double lsum = 0.0;
    for (int c = threadIdx.x; c < EDIM; c += 256) {
        const float xv = xrow[c];
        const float wv = wrow[c];
        const float t = wv - xv;       // f32 round, matches np (x_q - x)
        orow[c] = xv + t;              // f32 round, matches np STE output
        lsum += (double)t * (double)t;
    }
#pragma unroll
    for (int off = 32; off > 0; off >>= 1) lsum += __shfl_down(lsum, off, 64);
    __shared__ double part[4];
    const int lane = threadIdx.x & 63, w = threadIdx.x >> 6;
    if (lane == 0) part[w] = lsum;
    __syncthreads();
    if (threadIdx.x == 0) {
        atomicAdd(acc, part[0] + part[1] + part[2] + part[3]);
        out[XQSZ + 1 + row] = (float)idx;   // indices output (as f32 values)
    }
}

__global__ void k_finalize(float* __restrict__ out, const double* __restrict__ acc) {
    out[XQSZ] = (float)(0.25 * acc[0] / (double)XQSZ);
}

extern "C" void kernel_launch(void* const* d_in, const int* in_sizes, int n_in,
                              void* d_out, int out_size, void* d_ws, size_t ws_size,
                              hipStream_t stream) {
    const float* x = (const float*)d_in[0];
    // d_in[1] = label (unused), d_in[2] = idx (unused)
    const float* W = (const float*)d_in[3];
    float* out = (float*)d_out;
    char* ws = (char*)d_ws;

    double* acc = (double*)(ws + OFF_ACC);
    float* Z    = (float*)(ws + OFF_Z);
    float* c2   = (float*)(ws + OFF_C2);
    unsigned long long* keys = (unsigned long long*)(ws + OFF_KEYS);

    hipMemsetAsync(acc, 0, sizeof(double), stream);
    hipMemsetAsync(keys, 0xFF, NROWS * sizeof(unsigned long long), stream);
    k_rownorm<<<(NROWS + 255) / 256, 256, 0, stream>>>(x, Z, NROWS);
    k_rownorm<<<(NE + 255) / 256, 256, 0, stream>>>(W, c2, NE);
    k_argmin<<<dim3((NROWS / BM) * SPLIT), 256, 0, stream>>>(x, W, Z, c2, keys);
    k_gather<<<NROWS, 256, 0, stream>>>(x, W, keys, out, acc);
    k_finalize<<<1, 1, 0, stream>>>(out, acc);
}

// Round 5
// 1223.885 us; speedup vs baseline: 2.9987x; 1.5826x over previous
//
#include <hip/hip_runtime.h>
#include <cstdint>
#include <cstddef>

#define EDIM  512
#define NROWS 16384
#define NE    8192
#define XQSZ  (NROWS * EDIM)   // 8388608
#define K6    3072             // 6 * EDIM expanded K

// workspace byte offsets
#define OFF_ACC  0
#define OFF_Z    4096
#define OFF_C2   (OFF_Z + NROWS * 4)                 // 69632
#define OFF_KEYS (OFF_C2 + NE * 4)                   // 102400
#define OFF_XE   (OFF_KEYS + NROWS * 8)              // 233472
#define OFF_WE   (OFF_XE + (size_t)NROWS * K6 * 2)   // +100,663,296
#define WS_NEED  (OFF_WE + (size_t)NE * K6 * 2)      // ~151.2 MB

typedef __attribute__((ext_vector_type(8)))  short          short8;
typedef __attribute__((ext_vector_type(16))) float          f32x16;
typedef __attribute__((ext_vector_type(4)))  unsigned short u16x4;

// ---------------- rownorm (numpy pairwise order) ----------------
__global__ void k_rownorm(const float* __restrict__ in, float* __restrict__ out, int nrows) {
#pragma clang fp contract(off)
    int row = blockIdx.x * blockDim.x + threadIdx.x;
    if (row >= nrows) return;
    const float* p = in + (size_t)row * EDIM;
    float S[4];
#pragma unroll
    for (int b = 0; b < 4; ++b) {
        const float* q = p + b * 128;
        float r[8];
#pragma unroll
        for (int j = 0; j < 8; ++j) { float v = q[j]; r[j] = v * v; }
        for (int i = 8; i < 128; i += 8) {
#pragma unroll
            for (int j = 0; j < 8; ++j) { float v = q[i + j]; r[j] = r[j] + v * v; }
        }
        S[b] = ((r[0] + r[1]) + (r[2] + r[3])) + ((r[4] + r[5]) + (r[6] + r[7]));
    }
    out[row] = (S[0] + S[1]) + (S[2] + S[3]);
}

// ---------------- bf16 3-way split (exact decomposition) ----------------
__device__ __forceinline__ unsigned short f2bf(float f) {
    unsigned u = __float_as_uint(f);
    return (unsigned short)((u + 0x7FFFu + ((u >> 16) & 1u)) >> 16);
}
__device__ __forceinline__ float bf2f(unsigned short h) {
    return __uint_as_float(((unsigned)h) << 16);
}

// Expanded K layout: 6 blocks of EDIM columns. Product pairing per block:
//   b0: hi*MID  b1: mid*HI  b2: mid*MID  b3: hi*LO  b4: lo*HI  b5: hi*HI
// (small terms first; dominant hi*HI accumulates LAST -> error profile
//  matches a plain f32 summation, which round-4 proved matches np bitwise)
template<int ISW>
__global__ __launch_bounds__(256) void k_split(const float* __restrict__ in,
        unsigned short* __restrict__ outp, int nrows) {
    int e = blockIdx.x * 256 + threadIdx.x;
    int row = e >> 7;               // EDIM/4 = 128 float4-groups per row
    int d0  = (e & 127) << 2;
    if (row >= nrows) return;
    float4 v = *(const float4*)(in + (size_t)row * EDIM + d0);
    float vv[4] = {v.x, v.y, v.z, v.w};
    u16x4 H, M, L;
#pragma unroll
    for (int i = 0; i < 4; ++i) {
        float f = vv[i];
        unsigned short h = f2bf(f);
        float r1 = f - bf2f(h);          // exact (Sterbenz)
        unsigned short m = f2bf(r1);
        float r2 = r1 - bf2f(m);         // exact
        unsigned short l = f2bf(r2);
        H[i] = h; M[i] = m; L[i] = l;
    }
    unsigned short* o = outp + (size_t)row * K6 + d0;
    if (!ISW) {  // x side: [hi, mid, mid, hi, lo, hi]
        *(u16x4*)(o + 0*EDIM) = H; *(u16x4*)(o + 1*EDIM) = M; *(u16x4*)(o + 2*EDIM) = M;
        *(u16x4*)(o + 3*EDIM) = H; *(u16x4*)(o + 4*EDIM) = L; *(u16x4*)(o + 5*EDIM) = H;
    } else {     // W side: [MID, HI, MID, LO, HI, HI]
        *(u16x4*)(o + 0*EDIM) = M; *(u16x4*)(o + 1*EDIM) = H; *(u16x4*)(o + 2*EDIM) = M;
        *(u16x4*)(o + 3*EDIM) = L; *(u16x4*)(o + 4*EDIM) = H; *(u16x4*)(o + 5*EDIM) = H;
    }
}

// ---------------- MFMA GEMM-argmin ----------------
__device__ __forceinline__ void gld16(const void* g, void* l) {
    __builtin_amdgcn_global_load_lds((const __attribute__((address_space(1))) void*)g,
                                     (__attribute__((address_space(3))) void*)l, 16, 0, 0);
}

#define GBM 128
#define GBN 128
#define GBK 64

// 128x128 tile, 4 waves (2x2), each wave 64x64 via 2x2 frags of 32x32x16 bf16.
// LDS [row][k] bf16, 16B chunks; chunk index XOR-swizzled by (row&7) on the
// GLOBAL SOURCE side (global_load_lds writes linearly), un-swizzled on read.
__global__ __launch_bounds__(256) void k_mfma_argmin(
        const unsigned short* __restrict__ Xe, const unsigned short* __restrict__ We,
        const float* __restrict__ Z, const float* __restrict__ c2,
        unsigned long long* __restrict__ keys) {
    __shared__ __align__(16) unsigned short At[GBM * GBK];
    __shared__ __align__(16) unsigned short Bt[GBN * GBK];
    __shared__ float Zs[GBM];

    const int tid = threadIdx.x;
    const int lane = tid & 63, wid = tid >> 6;
    const int wr = wid >> 1, wc = wid & 1;

    // XCD-aware swizzle (8192 blocks, 8192 % 8 == 0 -> bijective)
    const int bid = blockIdx.x;
    const int swz = (bid & 7) * 1024 + (bid >> 3);
    const int rowtile = swz & 127, codetile = swz >> 7;
    const int row0 = rowtile * GBM, code0 = codetile * GBN;

    if (tid < GBM) Zs[tid] = Z[row0 + tid];

    f32x16 acc[2][2];
#pragma unroll
    for (int i = 0; i < 2; ++i)
#pragma unroll
        for (int j = 0; j < 2; ++j)
#pragma unroll
            for (int r = 0; r < 16; ++r) acc[i][j][r] = 0.0f;

    size_t ga[4], gb[4];
#pragma unroll
    for (int i = 0; i < 4; ++i) {
        int chunk = i * 256 + tid;          // 1024 chunks of 16B per tile
        int row   = chunk >> 3;             // 8 chunks per row (GBK*2/16)
        int kcs   = (chunk & 7) ^ (row & 7);  // pre-swizzled source chunk
        ga[i] = (size_t)(row0 + row) * K6 + kcs * 8;
        gb[i] = (size_t)(code0 + row) * K6 + kcs * 8;
    }

    const int ra0 = wr * 64 + (lane & 31);
    const int rb0 = wc * 64 + (lane & 31);
    const int kh  = lane >> 5;
    const int sa  = ra0 & 7, sb = rb0 & 7;   // read-side swizzle

    for (int kt = 0; kt < K6 / GBK; ++kt) {
        const size_t ko = (size_t)kt * GBK;
#pragma unroll
        for (int i = 0; i < 4; ++i) {
            gld16(Xe + ga[i] + ko, (char*)At + i * 4096 + wid * 1024);
            gld16(We + gb[i] + ko, (char*)Bt + i * 4096 + wid * 1024);
        }
        __syncthreads();
#pragma unroll
        for (int ks = 0; ks < 4; ++ks) {
            const int ch = ks * 2 + kh;     // logical 16B chunk within row
            short8 a0 = *(const short8*)((const char*)At + ra0 * 128        + ((ch ^ sa) * 16));
            short8 a1 = *(const short8*)((const char*)At + (ra0 + 32) * 128 + ((ch ^ sa) * 16));
            short8 b0 = *(const short8*)((const char*)Bt + rb0 * 128        + ((ch ^ sb) * 16));
            short8 b1 = *(const short8*)((const char*)Bt + (rb0 + 32) * 128 + ((ch ^ sb) * 16));
            acc[0][0] = __builtin_amdgcn_mfma_f32_32x32x16_bf16(a0, b0, acc[0][0], 0, 0, 0);
            acc[0][1] = __builtin_amdgcn_mfma_f32_32x32x16_bf16(a0, b1, acc[0][1], 0, 0, 0);
            acc[1][0] = __builtin_amdgcn_mfma_f32_32x32x16_bf16(a1, b0, acc[1][0], 0, 0, 0);
            acc[1][1] = __builtin_amdgcn_mfma_f32_32x32x16_bf16(a1, b1, acc[1][1], 0, 0, 0);
        }
        __syncthreads();
    }

    // epilogue: C layout (m74/m101): col = lane&31, row = (reg&3)+8*(reg>>2)+4*(lane>>5)
    const int j0 = code0 + wc * 64 + (lane & 31);
    const float c20 = c2[j0], c21 = c2[j0 + 32];
#pragma unroll
    for (int mi = 0; mi < 2; ++mi) {
#pragma unroll
        for (int reg = 0; reg < 16; ++reg) {
            const int rl = wr * 64 + mi * 32 + (reg & 3) + 8 * (reg >> 2) + 4 * kh;
            const float Zr = Zs[rl];
            const float d0 = (Zr + c20) - 2.0f * acc[mi][0][reg];
            const float d1 = (Zr + c21) - 2.0f * acc[mi][1][reg];
            unsigned long long k0 = (((unsigned long long)__float_as_uint(d0)) << 13) | (unsigned)j0;
            unsigned long long k1 = (((unsigned long long)__float_as_uint(d1)) << 13) | (unsigned)(j0 + 32);
            unsigned long long k = k0 < k1 ? k0 : k1;
#pragma unroll
            for (int m = 1; m <= 16; m <<= 1) {
                unsigned long long o = __shfl_xor(k, m, 64);
                if (o < k) k = o;
            }
            if ((lane & 31) == 0) atomicMin(&keys[row0 + rl], k);
        }
    }
}

// ---------------- fallback: proven round-4 VALU argmin ----------------
#define BM 128
#define BN 128
#define DC 32
#define SPLIT 8
#define CPB (NE / SPLIT)
#define NT  (CPB / BN)

__global__ __launch_bounds__(256, 4) void k_argmin_valu(
        const float* __restrict__ x, const float* __restrict__ W,
        const float* __restrict__ Z, const float* __restrict__ c2,
        unsigned long long* __restrict__ keys) {
    __shared__ __align__(16) unsigned char smem[(DC * BM + DC * BN + BM) * 4];
    float (*A)[BM] = reinterpret_cast<float (*)[BM]>(smem);
    float (*B)[BN] = reinterpret_cast<float (*)[BN]>(smem + DC * BM * 4);
    float* Zs      = reinterpret_cast<float*>(smem + (DC * BM + DC * BN) * 4);
    unsigned long long (*kb)[17] = reinterpret_cast<unsigned long long (*)[17]>(smem);

    const int tid = threadIdx.x;
    const int tx = tid & 15, ty = tid >> 4;
    const int rowtile = blockIdx.x & (NROWS / BM - 1);
    const int csplit  = blockIdx.x >> 7;
    const int row0 = rowtile * BM;
    const int code0 = csplit * CPB;

    if (tid < BM) Zs[tid] = Z[row0 + tid];
    __syncthreads();

    unsigned long long key[8];
#pragma unroll
    for (int i = 0; i < 8; ++i) key[i] = ~0ull;

    const int qa = tid & 7;
    const int ra = tid >> 3;
    const int wsw = qa << 2;

    for (int nt = 0; nt < NT; ++nt) {
        const int j0 = code0 + nt * BN;
        float acc[8][8];
#pragma unroll
        for (int i = 0; i < 8; ++i)
#pragma unroll
            for (int j = 0; j < 8; ++j) acc[i][j] = 0.0f;

        for (int dc = 0; dc < EDIM / DC; ++dc) {
            const int d0 = dc * DC;
#pragma unroll
            for (int s = 0; s < 4; ++s) {
                const int rr = ra + 32 * s;
                const int pc = rr ^ wsw ^ ((s & 3) << 2);
                const float4 av = *(const float4*)(x + (size_t)(row0 + rr) * EDIM + d0 + qa * 4);
                A[qa * 4 + 0][pc] = av.x; A[qa * 4 + 1][pc] = av.y;
                A[qa * 4 + 2][pc] = av.z; A[qa * 4 + 3][pc] = av.w;
                const float4 bv = *(const float4*)(W + (size_t)(j0 + rr) * EDIM + d0 + qa * 4);
                B[qa * 4 + 0][pc] = bv.x; B[qa * 4 + 1][pc] = bv.y;
                B[qa * 4 + 2][pc] = bv.z; B[qa * 4 + 3][pc] = bv.w;
            }
            __syncthreads();
#pragma unroll
            for (int dg = 0; dg < DC / 4; ++dg) {
                const int sw = (dg & 7) << 2;
                const int ca0 = ty * 8;
                const int pa0 = ca0 ^ sw ^ (((ca0 >> 5) & 3) << 2);
                const int pa1 = pa0 ^ 4;
                const int cb0 = tx * 8;
                const int pb0 = cb0 ^ sw ^ (((cb0 >> 5) & 3) << 2);
                const int pb1 = pb0 ^ 4;
#pragma unroll
                for (int dd = 0; dd < 4; ++dd) {
                    const int d = dg * 4 + dd;
                    const float4 a0 = *(const float4*)&A[d][pa0];
                    const float4 a1 = *(const float4*)&A[d][pa1];
                    const float4 b0 = *(const float4*)&B[d][pb0];
                    const float4 b1 = *(const float4*)&B[d][pb1];
                    const float a[8] = {a0.x, a0.y, a0.z, a0.w, a1.x, a1.y, a1.z, a1.w};
                    const float b[8] = {b0.x, b0.y, b0.z, b0.w, b1.x, b1.y, b1.z, b1.w};
#pragma unroll
                    for (int i = 0; i < 8; ++i)
#pragma unroll
                        for (int j = 0; j < 8; ++j)
                            acc[i][j] += a[i] * b[j];
                }
            }
            __syncthreads();
        }
#pragma unroll
        for (int mi = 0; mi < 8; ++mi) {
            const float Zr = Zs[ty * 8 + mi];
#pragma unroll
            for (int ji = 0; ji < 8; ++ji) {
                const int j = j0 + tx * 8 + ji;
                const float t = Zr + c2[j];
                const float dd = t - 2.0f * acc[mi][ji];
                const unsigned long long k =
                    (((unsigned long long)__float_as_uint(dd)) << 13) | (unsigned)j;
                if (k < key[mi]) key[mi] = k;
            }
        }
    }

    __syncthreads();
#pragma unroll
    for (int mi = 0; mi < 8; ++mi) kb[ty * 8 + mi][tx] = key[mi];
    __syncthreads();
    if (tid < BM) {
        unsigned long long m = kb[tid][0];
#pragma unroll
        for (int t = 1; t < 16; ++t) { unsigned long long v = kb[tid][t]; if (v < m) m = v; }
        atomicMin(&keys[row0 + tid], m);
    }
}

// ---------------- gather / loss / finalize ----------------
__global__ __launch_bounds__(256) void k_gather(
        const float* __restrict__ x, const float* __restrict__ W,
        const unsigned long long* __restrict__ keys,
        float* __restrict__ out, double* __restrict__ acc) {
    const int row = blockIdx.x;
    const int idx = (int)(keys[row] & 0x1FFFull);

    const float* wrow = W + (size_t)idx * EDIM;
    const float* xrow = x + (size_t)row * EDIM;
    float* orow = out + (size_t)row * EDIM;

    double lsum = 0.0;
    for (int c = threadIdx.x; c < EDIM; c += 256) {
        const float xv = xrow[c];
        const float wv = wrow[c];
        const float t = wv - xv;
        orow[c] = xv + t;
        lsum += (double)t * (double)t;
    }
#pragma unroll
    for (int off = 32; off > 0; off >>= 1) lsum += __shfl_down(lsum, off, 64);
    __shared__ double part[4];
    const int lane = threadIdx.x & 63, w = threadIdx.x >> 6;
    if (lane == 0) part[w] = lsum;
    __syncthreads();
    if (threadIdx.x == 0) {
        atomicAdd(acc, part[0] + part[1] + part[2] + part[3]);
        out[XQSZ + 1 + row] = (float)idx;
    }
}

__global__ void k_finalize(float* __restrict__ out, const double* __restrict__ acc) {
    out[XQSZ] = (float)(0.25 * acc[0] / (double)XQSZ);
}

extern "C" void kernel_launch(void* const* d_in, const int* in_sizes, int n_in,
                              void* d_out, int out_size, void* d_ws, size_t ws_size,
                              hipStream_t stream) {
    const float* x = (const float*)d_in[0];
    const float* W = (const float*)d_in[3];
    float* out = (float*)d_out;
    char* ws = (char*)d_ws;

    double* acc = (double*)(ws + OFF_ACC);
    float* Z    = (float*)(ws + OFF_Z);
    float* c2   = (float*)(ws + OFF_C2);
    unsigned long long* keys = (unsigned long long*)(ws + OFF_KEYS);
    unsigned short* Xe = (unsigned short*)(ws + OFF_XE);
    unsigned short* We = (unsigned short*)(ws + OFF_WE);

    const bool big = ws_size >= (size_t)WS_NEED;

    hipMemsetAsync(acc, 0, sizeof(double), stream);
    hipMemsetAsync(keys, 0xFF, NROWS * sizeof(unsigned long long), stream);
    k_rownorm<<<NROWS / 256, 256, 0, stream>>>(x, Z, NROWS);
    k_rownorm<<<NE / 256, 256, 0, stream>>>(W, c2, NE);
    if (big) {
        k_split<0><<<(NROWS * (EDIM / 4)) / 256, 256, 0, stream>>>(x, Xe, NROWS);
        k_split<1><<<(NE * (EDIM / 4)) / 256, 256, 0, stream>>>(W, We, NE);
        k_mfma_argmin<<<(NROWS / GBM) * (NE / GBN), 256, 0, stream>>>(Xe, We, Z, c2, keys);
    } else {
        k_argmin_valu<<<(NROWS / BM) * SPLIT, 256, 0, stream>>>(x, W, Z, c2, keys);
    }
    k_gather<<<NROWS, 256, 0, stream>>>(x, W, keys, out, acc);
    k_finalize<<<1, 1, 0, stream>>>(out, acc);
}